// Round 12
// baseline (47.200 us; speedup 1.0000x reference)
//
#include <hip/hip_runtime.h>
#include <math.h>

// Biquad peaking EQ over [B=8, C=2, T=1200000] f32.
// Round 12: ZERO-LDS maximum-occupancy variant.
// Round-11 probe: graph-node overhead = (41.95-29.07)/8 ~ 1.6us/kernel ->
// r9 exec ~27.5us vs ~18.5us floor. All LDS-staged variants (r5-r10) pinned
// at 29-31us regardless of pipelining -> buy wave concurrency instead:
//  - NO LDS, NO staging, NO fences, NO persistence, NO tables.
//  - Lane i owns one 128-B line (32 samples) in 8 x f32x4 registers.
//  - Pass 1: zero-state recurrence over own row -> exit state (v1,v2).
//  - Entry state via 4-term truncated series (4 independent shfl_up pairs,
//    e = v_{-1} + M32 v_{-2} + M64 v_{-3} + M96 v_{-4}; ||M^32||~0.1,
//    validated r8/r9, absmax 0.031 vs threshold 0.119).
//  - Pass 2: RE-RUN the recurrence with the corrected entry state (replaces
//    the LDS transpose + c1/c2 trig tables entirely; 3 FMA/sample, in-place).
//  - Store: lanes 4..63 write their own rows (16B x 8 at 128B wave stride;
//    the wave's 8-store burst fully covers each 128-B line -> L2 assembles).
//  - ~55 VGPR, __launch_bounds__(256,8) -> 8 waves/SIMD = 32 waves/CU,
//    2x r9's residency. 10000 single-segment waves, dispatcher backfills.
// Warm-up: lanes 0-3 (128 samples) compute but don't store; segment 0 per
// channel has exact zero prehistory. NO atomics (r6: hot line = 170us).

typedef float f32x4 __attribute__((ext_vector_type(4)));

#define T_LEN 1200000
#define NCH   16
#define L     32
#define NR    64
#define NWARM 4
#define OUT_ROWS (NR - NWARM)           // 60
#define OUT_PER_SEG (OUT_ROWS * L)      // 1920
#define SEGS_PER_CH (T_LEN / OUT_PER_SEG)   // 625 (exact)
#define NSEG (SEGS_PER_CH * NCH)        // 10000
#define WPB 4
#define NBLOCKS (NSEG / WPB)            // 2500 (exact)

struct Params {
    float b0, b1, b2, a1, a2;
    float C[3][4];                      // M^32, M^64, M^96 row-major
};

__global__ __launch_bounds__(256, 8) void eq_kernel(const float* __restrict__ x,
                                                    float* __restrict__ y, Params P)
{
    const int lane = threadIdx.x & 63;
    const int wid  = threadIdx.x >> 6;

    const int s  = blockIdx.x * WPB + wid;        // 0..9999, one segment per wave
    const int ch = s / SEGS_PER_CH;
    const int si = s - ch * SEGS_PER_CH;
    const float* __restrict__ xc = x + (size_t)ch * T_LEN;
    float*       __restrict__ yc = y + (size_t)ch * T_LEN;
    const int g0 = si * OUT_PER_SEG - NWARM * L;  // -128 only for si == 0
    const int gl = g0 + (lane << 5);              // lane's row start

    // ---- load own row: one 128-B line as 8 x f32x4 ----
    f32x4 r[8];
    #pragma unroll
    for (int k = 0; k < 8; ++k) {
        int g = gl + (k << 2);                    // multiple of 4; T_LEN % 4 == 0
        f32x4 v = {0.f, 0.f, 0.f, 0.f};
        if (g >= 0 && g < T_LEN) v = *(const f32x4*)(xc + g);
        r[k] = v;
    }

    // input tail of previous row from neighbor lane's registers
    float tx1 = __shfl_up(r[7].w, 1);             // x[-1]
    float tx2 = __shfl_up(r[7].z, 1);             // x[-2]
    if (lane == 0) { tx1 = 0.f; tx2 = 0.f; }      // exact for si==0; warm-up else

    // ---- pass 1: zero-state recurrence -> exit state (v1, v2) ----
    float v1 = 0.f, v2 = 0.f;
    {
        float x1 = tx1, x2 = tx2;
        #pragma unroll
        for (int b = 0; b < 8; ++b) {
            #pragma unroll
            for (int k = 0; k < 4; ++k) {
                float xk = r[b][k];
                float f  = fmaf(P.b0, xk, fmaf(P.b1, x1, P.b2 * x2));
                float t2 = fmaf(-P.a2, v2, f);
                float yk = fmaf(-P.a1, v1, t2);
                v2 = v1; v1 = yk;
                x2 = x1; x1 = xk;
            }
        }
    }

    // ---- entry state via truncated series (4 independent shuffles) ----
    float q11 = __shfl_up(v1, 1), q21 = __shfl_up(v2, 1);
    float q12 = __shfl_up(v1, 2), q22 = __shfl_up(v2, 2);
    float q13 = __shfl_up(v1, 3), q23 = __shfl_up(v2, 3);
    float q14 = __shfl_up(v1, 4), q24 = __shfl_up(v2, 4);
    if (lane < 1) { q11 = 0.f; q21 = 0.f; }
    if (lane < 2) { q12 = 0.f; q22 = 0.f; }
    if (lane < 3) { q13 = 0.f; q23 = 0.f; }
    if (lane < 4) { q14 = 0.f; q24 = 0.f; }
    float e1 = q11, e2 = q21;                     // e = y[-1], y[-2] of own row
    e1 = fmaf(P.C[0][0], q12, fmaf(P.C[0][1], q22, e1));
    e2 = fmaf(P.C[0][2], q12, fmaf(P.C[0][3], q22, e2));
    e1 = fmaf(P.C[1][0], q13, fmaf(P.C[1][1], q23, e1));
    e2 = fmaf(P.C[1][2], q13, fmaf(P.C[1][3], q23, e2));
    e1 = fmaf(P.C[2][0], q14, fmaf(P.C[2][1], q24, e1));
    e2 = fmaf(P.C[2][2], q14, fmaf(P.C[2][3], q24, e2));

    // ---- pass 2: true-state recurrence, y overwrites x in registers ----
    {
        float x1 = tx1, x2 = tx2, w1 = e1, w2 = e2;
        #pragma unroll
        for (int b = 0; b < 8; ++b) {
            f32x4 xv = r[b];
            f32x4 yv;
            #pragma unroll
            for (int k = 0; k < 4; ++k) {
                float xk = xv[k];
                float f  = fmaf(P.b0, xk, fmaf(P.b1, x1, P.b2 * x2));
                float t2 = fmaf(-P.a2, w2, f);
                float yk = fmaf(-P.a1, w1, t2);
                w2 = w1; w1 = yk;
                x2 = x1; x1 = xk;
                yv[k] = yk;
            }
            r[b] = yv;
        }
    }

    // ---- store own row (lanes 4..63): always in-bounds ----
    // gl >= g0+128 >= 0 and gl+31 <= si*1920+1919 < T_LEN.
    if (lane >= NWARM) {
        #pragma unroll
        for (int k = 0; k < 8; ++k)
            *(f32x4*)(yc + gl + (k << 2)) = r[k];
    }
}

extern "C" void kernel_launch(void* const* d_in, const int* in_sizes, int n_in,
                              void* d_out, int out_size, void* d_ws, size_t ws_size,
                              hipStream_t stream) {
    const float* x = (const float*)d_in[0];
    float* y = (float*)d_out;

    // torchaudio peaking-EQ coefficients (double, then cast — matches ref)
    double w0    = 2.0 * M_PI * 1000.0 / 44100.0;
    double A     = exp(6.0 / 40.0 * log(10.0));
    double al    = sin(w0) / (2.0 * 0.707);
    double b0 = 1.0 + al * A;
    double b1 = -2.0 * cos(w0);
    double b2 = 1.0 - al * A;
    double a0 = 1.0 + al / A;
    double a1 = -2.0 * cos(w0);
    double a2 = 1.0 - al / A;
    b0 /= a0; b1 /= a0; b2 /= a0; a1 /= a0; a2 /= a0;

    Params P;
    P.b0 = (float)b0; P.b1 = (float)b1; P.b2 = (float)b2;
    P.a1 = (float)a1; P.a2 = (float)a2;

    // M^32 via repeated squaring; then M^64, M^96 (double precision)
    double m00 = -a1, m01 = -a2, m10 = 1.0, m11 = 0.0;
    for (int s = 0; s < 5; ++s) {
        double t00 = m00 * m00 + m01 * m10;
        double t01 = m00 * m01 + m01 * m11;
        double t10 = m10 * m00 + m11 * m10;
        double t11 = m10 * m01 + m11 * m11;
        m00 = t00; m01 = t01; m10 = t10; m11 = t11;
    }
    double p00 = m00, p01 = m01, p10 = m10, p11 = m11;    // M^32
    for (int k = 0; k < 3; ++k) {
        P.C[k][0] = (float)p00; P.C[k][1] = (float)p01;
        P.C[k][2] = (float)p10; P.C[k][3] = (float)p11;
        double t00 = p00 * m00 + p01 * m10;               // * M^32
        double t01 = p00 * m01 + p01 * m11;
        double t10 = p10 * m00 + p11 * m10;
        double t11 = p10 * m01 + p11 * m11;
        p00 = t00; p01 = t01; p10 = t10; p11 = t11;
    }

    eq_kernel<<<NBLOCKS, 256, 0, stream>>>(x, y, P);
}